// Round 6
// baseline (359.879 us; speedup 1.0000x reference)
//
#include <hip/hip_runtime.h>
#include <hip/hip_bf16.h>
#include <math.h>

// Problem constants (B=2, S=2048, D=1024, H=16, dk=64)
#define BATCH 2
#define SEQ   2048
#define DMODEL 1024
#define NHEAD 16
#define DK    64
#define M_TOT (BATCH*SEQ)      // 4096
#define KDIM  DMODEL           // 1024

typedef short bf16x8 __attribute__((ext_vector_type(8)));
typedef short bf16x4 __attribute__((ext_vector_type(4)));
typedef float f32x4  __attribute__((ext_vector_type(4)));
typedef __hip_bfloat16 bf16;

// 0.125 * log2(e) : folded into Q projection so softmax is exp2 directly
#define QSCALE 0.18033688011112042f

__device__ inline void gld_lds16(const void* g, void* l) {
    __builtin_amdgcn_global_load_lds(
        (const __attribute__((address_space(1))) unsigned int*)g,
        (__attribute__((address_space(3))) unsigned int*)l, 16, 0, 0);
}

__device__ inline unsigned pack2(float a, float b) {
    union { __hip_bfloat162 h; unsigned u; } t;
    t.h = __float22bfloat162_rn(make_float2(a, b));
    return t.u;
}

// ---- fused pre-pass. y=0..2: q/k/v fp32->bf16 (4M elems each).
// y=3: the four 1M-elem weights packed into a 4M range (all hi-only now).
__global__ __launch_bounds__(256) void conv_all(
    const float* __restrict__ q, const float* __restrict__ k, const float* __restrict__ v,
    const float* __restrict__ wq, const float* __restrict__ wk,
    const float* __restrict__ wv, const float* __restrict__ wo,
    bf16* __restrict__ qh, bf16* __restrict__ kh, bf16* __restrict__ vh,
    bf16* __restrict__ wqh, bf16* __restrict__ wkh, bf16* __restrict__ wvh,
    bf16* __restrict__ woh)
{
    const int y = blockIdx.y;
    const int i = (blockIdx.x * 256 + threadIdx.x) * 4;
    if (y < 3) {
        const float* src = y == 0 ? q : (y == 1 ? k : v);
        bf16* dst = y == 0 ? qh : (y == 1 ? kh : vh);
        float4 t = *(const float4*)(src + i);
        uint2 o;
        o.x = pack2(t.x, t.y);
        o.y = pack2(t.z, t.w);
        *(uint2*)(dst + i) = o;
    } else {
        const int w = i >> 20;               // 0..3 -> wq,wk,wv,wo
        const int j = i & ((1 << 20) - 1);
        const float* src = w == 0 ? wq : (w == 1 ? wk : (w == 2 ? wv : wo));
        bf16* dsth = w == 0 ? wqh : (w == 1 ? wkh : (w == 2 ? wvh : woh));
        float4 t = *(const float4*)(src + j);
        uint2 oh;
        oh.x = pack2(t.x, t.y);
        oh.y = pack2(t.z, t.w);
        *(uint2*)(dsth + j) = oh;
    }
}

// ---- MFMA GEMM body: C[M,N] = A @ W^T (+ bias), bf16 [rows, 1024].
// 128x128 tile, BK=32, 4 waves.
// layout 0: f32 [M,1024] +bias; 1: bf16 [B,H,S,dk] (*scale); 2: bf16 [B,H,dk,S];
// layout 3: f32 [M,1024] raw partial (no bias).  K range [kb, ke).
__device__ __forceinline__ void gemm_body(
    const bf16* __restrict__ Ah, const bf16* __restrict__ Wh,
    const float* __restrict__ bias, void* __restrict__ out,
    int layout, float scale, bf16* sA, bf16* sB, int kb, int ke)
{
    const int tid  = threadIdx.x;
    const int wave = tid >> 6, lane = tid & 63;
    const int ln   = lane & 15, quad = lane >> 4;
    const int wm   = wave >> 1, wn = wave & 1;
    const int row0 = blockIdx.y * 128, col0 = blockIdx.x * 128;

    const int srow = lane >> 2;
    const int clog = (lane & 3) ^ (srow & 3);
    const size_t gA0 = (size_t)(row0 + wave * 16 + srow) * KDIM + clog * 8;
    const size_t gB0 = (size_t)(col0 + wave * 16 + srow) * KDIM + clog * 8;
    const int ldsoff = (wave * 16 + srow) * 64 + (lane & 3) * 16;   // bytes

    const int swz = (quad ^ (ln & 3)) * 8;

    f32x4 acc[4][4] = {};

    for (int k0 = kb; k0 < ke; k0 += 32) {
        __syncthreads();
#pragma unroll
        for (int j = 0; j < 2; ++j) {
            const size_t go = (size_t)k0 + (size_t)j * 64 * KDIM;
            gld_lds16(Ah + gA0 + go, (char*)sA + j * 4096 + ldsoff);
            gld_lds16(Wh + gB0 + go, (char*)sB + j * 4096 + ldsoff);
        }
        __syncthreads();

        bf16x8 af[4], bfr[4];
#pragma unroll
        for (int t = 0; t < 4; ++t) {
            af[t]  = *(const bf16x8*)&sA[(wm * 64 + t * 16 + ln) * 32 + swz];
            bfr[t] = *(const bf16x8*)&sB[(wn * 64 + t * 16 + ln) * 32 + swz];
        }
#pragma unroll
        for (int mt = 0; mt < 4; ++mt)
#pragma unroll
            for (int nt = 0; nt < 4; ++nt)
                acc[mt][nt] = __builtin_amdgcn_mfma_f32_16x16x32_bf16(af[mt], bfr[nt], acc[mt][nt], 0, 0, 0);
    }

#pragma unroll
    for (int nt = 0; nt < 4; ++nt) {
        const int n = col0 + wn * 64 + nt * 16 + ln;
        const float bv = (layout == 3) ? 0.f : bias[n];
#pragma unroll
        for (int mt = 0; mt < 4; ++mt) {
#pragma unroll
            for (int r = 0; r < 4; ++r) {
                const int m = row0 + wm * 64 + mt * 16 + quad * 4 + r;
                const float v = (acc[mt][nt][r] + bv) * scale;
                if (layout == 0 || layout == 3) {
                    ((float*)out)[(size_t)m * DMODEL + n] = v;
                } else {
                    const int b = m >> 11, s = m & (SEQ - 1);
                    const int h = n >> 6,  d = n & (DK - 1);
                    const int bh = b * NHEAD + h;
                    bf16 hv = __float2bfloat16(v);
                    if (layout == 1)
                        ((bf16*)out)[((size_t)bh * SEQ + s) * DK + d] = hv;
                    else
                        ((bf16*)out)[((size_t)bh * DK + d) * SEQ + s] = hv;
                }
            }
        }
    }
}

struct QKVArgs {
    const bf16* A[3];
    const bf16* W[3];
    const float* bias[3];
    bf16* out[3];
    float scale[3];
    int layout[3];
};

__global__ __launch_bounds__(256) void qkv_gemm(QKVArgs a) {
    __shared__ __align__(16) bf16 sA[128 * 32];
    __shared__ __align__(16) bf16 sB[128 * 32];
    const int z = blockIdx.z;
    gemm_body(a.A[z], a.W[z], a.bias[z],
              (void*)a.out[z], a.layout[z], a.scale[z], sA, sB, 0, KDIM);
}

// O projection, plain bf16, split-K x2: z selects K half, f32 partial.
__global__ __launch_bounds__(256) void gemm_o(
    const bf16* __restrict__ Ah, const bf16* __restrict__ Wh,
    float* __restrict__ p0, float* __restrict__ p1)
{
    __shared__ __align__(16) bf16 sA[128 * 32];
    __shared__ __align__(16) bf16 sB[128 * 32];
    const int z = blockIdx.z;
    gemm_body(Ah, Wh, nullptr, (void*)(z ? p1 : p0), 3, 1.0f,
              sA, sB, z * (KDIM / 2), (z + 1) * (KDIM / 2));
}

__global__ __launch_bounds__(256) void combine_o(
    const float* __restrict__ p0, const float* __restrict__ p1,
    const float* __restrict__ bias, float* __restrict__ out)
{
    const int i = (blockIdx.x * 256 + threadIdx.x) * 4;
    float4 a = *(const float4*)(p0 + i);
    float4 b = *(const float4*)(p1 + i);
    float4 c = *(const float4*)(bias + (i & (DMODEL - 1)));
    float4 o;
    o.x = a.x + b.x + c.x;
    o.y = a.y + b.y + c.y;
    o.z = a.z + b.z + c.z;
    o.w = a.w + b.w + c.w;
    *(float4*)(out + i) = o;
}

// ---- MFMA flash attention, BARRIER-FREE: no LDS at all.
// r3/r4/r5 lesson: the 2-barrier V-staging structure is the wall (occupancy
// x2 = null; de-drain = regression). Fix: PV B-frags are 4 consecutive kv
// in the Vpt [B,H,dk,S] layout -> direct 8B global loads, like K frags.
// V tile (8KB) is identical across the 4 waves -> L1 dedupes; K/V per head
// (256KB each) are L2-resident. No LDS -> no barriers -> waves fully
// independent; K double-register prefetch pipelines freely (no drain
// points exist). exp2 direct, no running max. 32 q/wave, 128 q/block.
#define NKT (SEQ / 64)
__global__ __launch_bounds__(256, 2) void flash_attn_mfma(
    const bf16* __restrict__ Q, const bf16* __restrict__ K,
    const bf16* __restrict__ Vt, bf16* __restrict__ ctxh)
{
    const int tid  = threadIdx.x;
    const int wave = tid >> 6, lane = tid & 63;
    const int ln   = lane & 15, quad = lane >> 4;
    const int qt   = blockIdx.x;     // 128-row q tile
    const int bh   = blockIdx.y;
    const int b    = bh >> 4, h = bh & (NHEAD - 1);

    const int q0 = qt * 128 + wave * 32;
    const bf16* Qb = Q + ((size_t)bh * SEQ + q0) * DK;
    bf16x8 qf[2][2];
#pragma unroll
    for (int c = 0; c < 2; ++c)
#pragma unroll
        for (int nt = 0; nt < 2; ++nt)
            qf[c][nt] = *(const bf16x8*)(Qb + (size_t)(nt * 16 + ln) * DK + c * 32 + quad * 8);

    f32x4 of[2][4] = {};
    float lp[2] = {0.f, 0.f};

    // K frag base: lane ln = kv row within 16-group, quad*8 = dk chunk
    const bf16* Kl = K + (size_t)bh * SEQ * DK + (size_t)ln * DK + quad * 8;
    // V frag base: lane ln = dk row within 16-group, quad*4 = kv sub-chunk
    const bf16* Vl = Vt + ((size_t)bh * DK + ln) * SEQ + quad * 4;

    // prologue: K frags tile 0 -> kfA
    bf16x8 kfA[2][4], kfB[2][4];
#pragma unroll
    for (int c = 0; c < 2; ++c)
#pragma unroll
        for (int mt = 0; mt < 4; ++mt)
            kfA[c][mt] = *(const bf16x8*)(Kl + (size_t)(mt * 16) * DK + c * 32);

    auto halfiter = [&](int ktc, bf16x8 (&kfc)[2][4], bf16x8 (&kfn)[2][4]) {
        // V frags for THIS tile, direct from global (16 x 8B loads);
        // latency covered by QK^T + exp2 below.
        bf16x4 vf[4][4];
#pragma unroll
        for (int mt = 0; mt < 4; ++mt)
#pragma unroll
            for (int nt = 0; nt < 4; ++nt)
                vf[mt][nt] = *(const bf16x4*)(Vl + (size_t)(nt * 16) * SEQ + ktc * 64 + mt * 16);

        // prefetch next tile's K frags into the alternate register set
        const int ktn = (ktc + 1) & (NKT - 1);
#pragma unroll
        for (int c = 0; c < 2; ++c)
#pragma unroll
            for (int mt = 0; mt < 4; ++mt)
                kfn[c][mt] = *(const bf16x8*)(Kl + (size_t)(ktn * 64 + mt * 16) * DK + c * 32);

        // S^T[kv=64][q=32] = K @ Q^T  (x32 MFMA)
        f32x4 st[4][2] = {};
#pragma unroll
        for (int c = 0; c < 2; ++c)
#pragma unroll
            for (int mt = 0; mt < 4; ++mt)
#pragma unroll
                for (int nt = 0; nt < 2; ++nt)
                    st[mt][nt] = __builtin_amdgcn_mfma_f32_16x16x32_bf16(kfc[c][mt], qf[c][nt], st[mt][nt], 0, 0, 0);

        // P = exp2(S) -> x16 A-frags in registers; lp partials
        bf16x4 aP[4][2];
#pragma unroll
        for (int mt = 0; mt < 4; ++mt)
#pragma unroll
            for (int nt = 0; nt < 2; ++nt) {
                float p0 = __builtin_amdgcn_exp2f(st[mt][nt][0]);
                float p1 = __builtin_amdgcn_exp2f(st[mt][nt][1]);
                float p2 = __builtin_amdgcn_exp2f(st[mt][nt][2]);
                float p3 = __builtin_amdgcn_exp2f(st[mt][nt][3]);
                lp[nt] += (p0 + p1) + (p2 + p3);
                union { bf16x4 v; uint2 u; } uu;
                uu.u.x = pack2(p0, p1);
                uu.u.y = pack2(p2, p3);
                aP[mt][nt] = uu.v;
            }

        // O[q=32][dk=64] += P @ V  (x16 MFMA, A and B both from registers)
#pragma unroll
        for (int mt = 0; mt < 4; ++mt)
#pragma unroll
            for (int nt = 0; nt < 4; ++nt) {
                of[0][nt] = __builtin_amdgcn_mfma_f32_16x16x16bf16_1k(aP[mt][0], vf[mt][nt], of[0][nt], 0, 0, 0);
                of[1][nt] = __builtin_amdgcn_mfma_f32_16x16x16bf16_1k(aP[mt][1], vf[mt][nt], of[1][nt], 0, 0, 0);
            }
    };

    for (int kt = 0; kt < NKT; kt += 2) {
        halfiter(kt,     kfA, kfB);
        halfiter(kt + 1, kfB, kfA);
    }

    // row-sum reduce over quads; then fetch per-O-row inverse
#pragma unroll
    for (int nt = 0; nt < 2; ++nt) {
        lp[nt] += __shfl_xor(lp[nt], 16, 64);
        lp[nt] += __shfl_xor(lp[nt], 32, 64);
    }
    float linv[2][4];
#pragma unroll
    for (int mtP = 0; mtP < 2; ++mtP)
#pragma unroll
        for (int r = 0; r < 4; ++r)
            linv[mtP][r] = 1.0f / __shfl(lp[mtP], quad * 4 + r, 64);

    const size_t base = ((size_t)b * SEQ + q0) * DMODEL + h * DK;
#pragma unroll
    for (int mtP = 0; mtP < 2; ++mtP)
#pragma unroll
        for (int nt = 0; nt < 4; ++nt)
#pragma unroll
            for (int r = 0; r < 4; ++r) {
                const float v = of[mtP][nt][r] * linv[mtP][r];
                const size_t idx = base + (size_t)(mtP * 16 + quad * 4 + r) * DMODEL + nt * 16 + ln;
                ctxh[idx] = __float2bfloat16(v);
            }
}

extern "C" void kernel_launch(void* const* d_in, const int* in_sizes, int n_in,
                              void* d_out, int out_size, void* d_ws, size_t ws_size,
                              hipStream_t stream) {
    const float* q  = (const float*)d_in[0];
    const float* k  = (const float*)d_in[1];
    const float* v  = (const float*)d_in[2];
    const float* wq = (const float*)d_in[3];
    const float* bq = (const float*)d_in[4];
    const float* wk = (const float*)d_in[5];
    const float* bk = (const float*)d_in[6];
    const float* wv = (const float*)d_in[7];
    const float* bv = (const float*)d_in[8];
    const float* wo = (const float*)d_in[9];
    const float* bo = (const float*)d_in[10];
    float* out = (float*)d_out;

    char* ws = (char*)d_ws;
    const size_t MB = 1u << 20;
    bf16* wq_hi = (bf16*)(ws + 0 * MB);    // 2 MB each
    bf16* wk_hi = (bf16*)(ws + 2 * MB);
    bf16* wv_hi = (bf16*)(ws + 4 * MB);
    bf16* wo_hi = (bf16*)(ws + 6 * MB);
    bf16* q_hi  = (bf16*)(ws + 8 * MB);    // 8 MB each; dead after qkv_gemm
    bf16* k_hi  = (bf16*)(ws + 16 * MB);
    bf16* v_hi  = (bf16*)(ws + 24 * MB);
    bf16* Qp    = (bf16*)(ws + 32 * MB);   // dead after flash
    bf16* Kp    = (bf16*)(ws + 40 * MB);
    bf16* Vpt   = (bf16*)(ws + 48 * MB);
    bf16* ctx_h = (bf16*)(ws + 8 * MB);    // overlays dead q_hi
    float* p0   = (float*)(ws + 16 * MB);  // 16 MB, overlays dead k_hi/v_hi
    float* p1   = (float*)(ws + 32 * MB);  // 16 MB, overlays dead Qp/Kp

    const int NX = M_TOT * DMODEL;   // 4M

    conv_all<<<dim3(NX / 1024, 4), 256, 0, stream>>>(
        q, k, v, wq, wk, wv, wo,
        q_hi, k_hi, v_hi, wq_hi, wk_hi, wv_hi, wo_hi);

    QKVArgs qa;
    qa.A[0] = q_hi;  qa.A[1] = k_hi;  qa.A[2] = v_hi;
    qa.W[0] = wq_hi; qa.W[1] = wk_hi; qa.W[2] = wv_hi;
    qa.bias[0] = bq; qa.bias[1] = bk; qa.bias[2] = bv;
    qa.out[0] = Qp;  qa.out[1] = Kp;  qa.out[2] = Vpt;
    qa.scale[0] = QSCALE; qa.scale[1] = 1.0f; qa.scale[2] = 1.0f;
    qa.layout[0] = 1; qa.layout[1] = 1; qa.layout[2] = 2;

    dim3 qgrid(DMODEL / 128, M_TOT / 128, 3);   // (8, 32, 3)
    qkv_gemm<<<qgrid, 256, 0, stream>>>(qa);

    dim3 fgrid(SEQ / 128, BATCH * NHEAD);       // (16, 32) = 512 blocks
    flash_attn_mfma<<<fgrid, 256, 0, stream>>>(Qp, Kp, Vpt, ctx_h);

    dim3 ogrid(DMODEL / 128, M_TOT / 128, 2);   // (8, 32, 2) split-K
    gemm_o<<<ogrid, 256, 0, stream>>>(ctx_h, wo_hi, p0, p1);

    combine_o<<<NX / 1024, 256, 0, stream>>>(p0, p1, bo, out);
}

// Round 7
// 303.822 us; speedup vs baseline: 1.1845x; 1.1845x over previous
//
#include <hip/hip_runtime.h>
#include <hip/hip_bf16.h>
#include <math.h>

// Problem constants (B=2, S=2048, D=1024, H=16, dk=64)
#define BATCH 2
#define SEQ   2048
#define DMODEL 1024
#define NHEAD 16
#define DK    64
#define M_TOT (BATCH*SEQ)      // 4096
#define KDIM  DMODEL           // 1024

typedef short bf16x8 __attribute__((ext_vector_type(8)));
typedef short bf16x4 __attribute__((ext_vector_type(4)));
typedef float f32x4  __attribute__((ext_vector_type(4)));
typedef __hip_bfloat16 bf16;

// 0.125 * log2(e) : folded into Q projection so softmax is exp2 directly
#define QSCALE 0.18033688011112042f

__device__ inline void gld_lds16(const void* g, void* l) {
    __builtin_amdgcn_global_load_lds(
        (const __attribute__((address_space(1))) unsigned int*)g,
        (__attribute__((address_space(3))) unsigned int*)l, 16, 0, 0);
}

__device__ inline unsigned pack2(float a, float b) {
    union { __hip_bfloat162 h; unsigned u; } t;
    t.h = __float22bfloat162_rn(make_float2(a, b));
    return t.u;
}

// ---- fused pre-pass. y=0..2: q/k/v fp32->bf16 (4M elems each).
// y=3: the four 1M-elem weights packed into a 4M range (all hi-only now).
__global__ __launch_bounds__(256) void conv_all(
    const float* __restrict__ q, const float* __restrict__ k, const float* __restrict__ v,
    const float* __restrict__ wq, const float* __restrict__ wk,
    const float* __restrict__ wv, const float* __restrict__ wo,
    bf16* __restrict__ qh, bf16* __restrict__ kh, bf16* __restrict__ vh,
    bf16* __restrict__ wqh, bf16* __restrict__ wkh, bf16* __restrict__ wvh,
    bf16* __restrict__ woh)
{
    const int y = blockIdx.y;
    const int i = (blockIdx.x * 256 + threadIdx.x) * 4;
    if (y < 3) {
        const float* src = y == 0 ? q : (y == 1 ? k : v);
        bf16* dst = y == 0 ? qh : (y == 1 ? kh : vh);
        float4 t = *(const float4*)(src + i);
        uint2 o;
        o.x = pack2(t.x, t.y);
        o.y = pack2(t.z, t.w);
        *(uint2*)(dst + i) = o;
    } else {
        const int w = i >> 20;               // 0..3 -> wq,wk,wv,wo
        const int j = i & ((1 << 20) - 1);
        const float* src = w == 0 ? wq : (w == 1 ? wk : (w == 2 ? wv : wo));
        bf16* dsth = w == 0 ? wqh : (w == 1 ? wkh : (w == 2 ? wvh : woh));
        float4 t = *(const float4*)(src + j);
        uint2 oh;
        oh.x = pack2(t.x, t.y);
        oh.y = pack2(t.z, t.w);
        *(uint2*)(dsth + j) = oh;
    }
}

// ---- MFMA GEMM body: C[M,N] = A @ W^T (+ bias), bf16 [rows, 1024].
// 128x128 tile, BK=32, 4 waves.
// layout 0: f32 [M,1024] +bias; 1: bf16 [B,H,S,dk] (*scale); 2: bf16 [B,H,dk,S];
// layout 3: f32 [M,1024] raw partial (no bias).  K range [kb, ke).
__device__ __forceinline__ void gemm_body(
    const bf16* __restrict__ Ah, const bf16* __restrict__ Wh,
    const float* __restrict__ bias, void* __restrict__ out,
    int layout, float scale, bf16* sA, bf16* sB, int kb, int ke)
{
    const int tid  = threadIdx.x;
    const int wave = tid >> 6, lane = tid & 63;
    const int ln   = lane & 15, quad = lane >> 4;
    const int wm   = wave >> 1, wn = wave & 1;
    const int row0 = blockIdx.y * 128, col0 = blockIdx.x * 128;

    const int srow = lane >> 2;
    const int clog = (lane & 3) ^ (srow & 3);
    const size_t gA0 = (size_t)(row0 + wave * 16 + srow) * KDIM + clog * 8;
    const size_t gB0 = (size_t)(col0 + wave * 16 + srow) * KDIM + clog * 8;
    const int ldsoff = (wave * 16 + srow) * 64 + (lane & 3) * 16;   // bytes

    const int swz = (quad ^ (ln & 3)) * 8;

    f32x4 acc[4][4] = {};

    for (int k0 = kb; k0 < ke; k0 += 32) {
        __syncthreads();
#pragma unroll
        for (int j = 0; j < 2; ++j) {
            const size_t go = (size_t)k0 + (size_t)j * 64 * KDIM;
            gld_lds16(Ah + gA0 + go, (char*)sA + j * 4096 + ldsoff);
            gld_lds16(Wh + gB0 + go, (char*)sB + j * 4096 + ldsoff);
        }
        __syncthreads();

        bf16x8 af[4], bfr[4];
#pragma unroll
        for (int t = 0; t < 4; ++t) {
            af[t]  = *(const bf16x8*)&sA[(wm * 64 + t * 16 + ln) * 32 + swz];
            bfr[t] = *(const bf16x8*)&sB[(wn * 64 + t * 16 + ln) * 32 + swz];
        }
#pragma unroll
        for (int mt = 0; mt < 4; ++mt)
#pragma unroll
            for (int nt = 0; nt < 4; ++nt)
                acc[mt][nt] = __builtin_amdgcn_mfma_f32_16x16x32_bf16(af[mt], bfr[nt], acc[mt][nt], 0, 0, 0);
    }

#pragma unroll
    for (int nt = 0; nt < 4; ++nt) {
        const int n = col0 + wn * 64 + nt * 16 + ln;
        const float bv = (layout == 3) ? 0.f : bias[n];
#pragma unroll
        for (int mt = 0; mt < 4; ++mt) {
#pragma unroll
            for (int r = 0; r < 4; ++r) {
                const int m = row0 + wm * 64 + mt * 16 + quad * 4 + r;
                const float v = (acc[mt][nt][r] + bv) * scale;
                if (layout == 0 || layout == 3) {
                    ((float*)out)[(size_t)m * DMODEL + n] = v;
                } else {
                    const int b = m >> 11, s = m & (SEQ - 1);
                    const int h = n >> 6,  d = n & (DK - 1);
                    const int bh = b * NHEAD + h;
                    bf16 hv = __float2bfloat16(v);
                    if (layout == 1)
                        ((bf16*)out)[((size_t)bh * SEQ + s) * DK + d] = hv;
                    else
                        ((bf16*)out)[((size_t)bh * DK + d) * SEQ + s] = hv;
                }
            }
        }
    }
}

struct QKVArgs {
    const bf16* A[3];
    const bf16* W[3];
    const float* bias[3];
    bf16* out[3];
    float scale[3];
    int layout[3];
};

__global__ __launch_bounds__(256) void qkv_gemm(QKVArgs a) {
    __shared__ __align__(16) bf16 sA[128 * 32];
    __shared__ __align__(16) bf16 sB[128 * 32];
    const int z = blockIdx.z;
    gemm_body(a.A[z], a.W[z], a.bias[z],
              (void*)a.out[z], a.layout[z], a.scale[z], sA, sB, 0, KDIM);
}

// O projection, plain bf16, split-K x2: z selects K half, f32 partial.
__global__ __launch_bounds__(256) void gemm_o(
    const bf16* __restrict__ Ah, const bf16* __restrict__ Wh,
    float* __restrict__ p0, float* __restrict__ p1)
{
    __shared__ __align__(16) bf16 sA[128 * 32];
    __shared__ __align__(16) bf16 sB[128 * 32];
    const int z = blockIdx.z;
    gemm_body(Ah, Wh, nullptr, (void*)(z ? p1 : p0), 3, 1.0f,
              sA, sB, z * (KDIM / 2), (z + 1) * (KDIM / 2));
}

__global__ __launch_bounds__(256) void combine_o(
    const float* __restrict__ p0, const float* __restrict__ p1,
    const float* __restrict__ bias, float* __restrict__ out)
{
    const int i = (blockIdx.x * 256 + threadIdx.x) * 4;
    float4 a = *(const float4*)(p0 + i);
    float4 b = *(const float4*)(p1 + i);
    float4 c = *(const float4*)(bias + (i & (DMODEL - 1)));
    float4 o;
    o.x = a.x + b.x + c.x;
    o.y = a.y + b.y + c.y;
    o.z = a.z + b.z + c.z;
    o.w = a.w + b.w + c.w;
    *(float4*)(out + i) = o;
}

// ---- MFMA flash attention: round-0 proven structure (256 thr, 4 waves,
// 32 q/wave, standard __syncthreads barriers) + two latency fixes:
// 1) XCD swizzle: the 16 blocks of one head land on one XCD (4 heads/XCD,
//    2MB KV fits the 4MB per-XCD L2). r0 FETCH=70MB showed ~4x KV HBM
//    re-fetch from cross-XCD scatter.
// 2) V[t+1] global load issued during tile t's compute phase into a second
//    register buffer (like K). The __syncthreads vmcnt(0) drain still
//    happens, but the load has the full compute phase to land -> drain ~0.
//    (r6 proved V must stay LDS-staged for coalescing; r5 proved raw
//    barriers + sched_barrier pins regress — so barriers stay standard.)
// exp2 direct, no running max.
#define NKT (SEQ / 64)
__global__ __launch_bounds__(256) void flash_attn_mfma(
    const bf16* __restrict__ Q, const bf16* __restrict__ K,
    const bf16* __restrict__ Vt, bf16* __restrict__ ctxh)
{
    __shared__ __align__(16) bf16 Vts[64 * 64];

    const int tid  = threadIdx.x;
    const int wave = tid >> 6, lane = tid & 63;
    const int ln   = lane & 15, quad = lane >> 4;

    // XCD-aware swizzle (bijective on 512 blocks = 8 xcd * 4 heads * 16 qt):
    // dispatch index lin -> xcd = lin%8; all 16 q-tiles of a head share it.
    const int lin  = blockIdx.y * gridDim.x + blockIdx.x;   // 0..511
    const int slot = lin >> 3;                              // 0..63
    const int bh   = (lin & 7) * 4 + (slot >> 4);           // 4 heads per XCD
    const int qt   = slot & 15;                             // 128-row q tile
    const int b    = bh >> 4, h = bh & (NHEAD - 1);

    const int q0 = qt * 128 + wave * 32;
    const bf16* Qb = Q + ((size_t)bh * SEQ + q0) * DK;
    bf16x8 qf[2][2];
#pragma unroll
    for (int c = 0; c < 2; ++c)
#pragma unroll
        for (int nt = 0; nt < 2; ++nt)
            qf[c][nt] = *(const bf16x8*)(Qb + (size_t)(nt * 16 + ln) * DK + c * 32 + quad * 8);

    f32x4 of[2][4] = {};
    float lp[2] = {0.f, 0.f};

    const int sr  = tid >> 2;          // 0..63 (dk row of Vt)
    const int scb = (tid & 3) * 2;
    const int ssw = sr & 7;
    const bf16* Vg0 = Vt + ((size_t)bh * DK + sr) * SEQ;
    const bf16* Kl  = K + (size_t)bh * SEQ * DK + (size_t)ln * DK + quad * 8;
    bf16* vdst = &Vts[sr * 64];

    // PV B-frag LDS addresses (kt-invariant, elements)
    int vaddr[4];
#pragma unroll
    for (int mt = 0; mt < 4; ++mt)
        vaddr[mt] = ln * 64 + (((2 * mt + (quad >> 1)) ^ (ln & 7)) * 8) + (quad & 1) * 4;

    // prologue: K frags + V tile 0 into buffer A
    bf16x8 kfA[2][4], kfB[2][4];
#pragma unroll
    for (int c = 0; c < 2; ++c)
#pragma unroll
        for (int mt = 0; mt < 4; ++mt)
            kfA[c][mt] = *(const bf16x8*)(Kl + (size_t)(mt * 16) * DK + c * 32);

    uint4 vpA[2], vpB[2];
    vpA[0] = *(const uint4*)(Vg0 + scb * 8);
    vpA[1] = *(const uint4*)(Vg0 + scb * 8 + 8);

    auto halfiter = [&](int ktc, bf16x8 (&kfc)[2][4], bf16x8 (&kfn)[2][4],
                        uint4 (&vpc)[2], uint4 (&vpn)[2]) {
        // barrier #1: waves done reading Vts[t-1]; drains K[t]/V[t] loads
        // that were issued at the TOP of the previous compute phase -> fast.
        __syncthreads();

        // write prefetched V[t] registers -> LDS (swizzled)
        *(uint4*)(vdst + ((scb    ) ^ ssw) * 8) = vpc[0];
        *(uint4*)(vdst + ((scb + 1) ^ ssw) * 8) = vpc[1];

        // barrier #2: V tile visible (nothing new in flight -> cheap drain)
        __syncthreads();

        // compute phase: FIRST issue next tile's K and V global loads so
        // their latency hides under this tile's MFMA+exp2 work.
        const int ktn = (ktc + 1) & (NKT - 1);
#pragma unroll
        for (int c = 0; c < 2; ++c)
#pragma unroll
            for (int mt = 0; mt < 4; ++mt)
                kfn[c][mt] = *(const bf16x8*)(Kl + (size_t)(ktn * 64 + mt * 16) * DK + c * 32);
        {
            const bf16* Vg = Vg0 + ktn * 64;
            vpn[0] = *(const uint4*)(Vg + scb * 8);
            vpn[1] = *(const uint4*)(Vg + scb * 8 + 8);
        }

        // S^T[kv=64][q=32] = K @ Q^T  (x32 MFMA)
        f32x4 st[4][2] = {};
#pragma unroll
        for (int c = 0; c < 2; ++c)
#pragma unroll
            for (int mt = 0; mt < 4; ++mt)
#pragma unroll
                for (int nt = 0; nt < 2; ++nt)
                    st[mt][nt] = __builtin_amdgcn_mfma_f32_16x16x32_bf16(kfc[c][mt], qf[c][nt], st[mt][nt], 0, 0, 0);

        // P = exp2(S) -> x16 A-frags in registers; lp partials
        bf16x4 aP[4][2];
#pragma unroll
        for (int mt = 0; mt < 4; ++mt)
#pragma unroll
            for (int nt = 0; nt < 2; ++nt) {
                float p0 = __builtin_amdgcn_exp2f(st[mt][nt][0]);
                float p1 = __builtin_amdgcn_exp2f(st[mt][nt][1]);
                float p2 = __builtin_amdgcn_exp2f(st[mt][nt][2]);
                float p3 = __builtin_amdgcn_exp2f(st[mt][nt][3]);
                lp[nt] += (p0 + p1) + (p2 + p3);
                union { bf16x4 v; uint2 u; } uu;
                uu.u.x = pack2(p0, p1);
                uu.u.y = pack2(p2, p3);
                aP[mt][nt] = uu.v;
            }

        // O[q=32][dk=64] += P @ V  (x16 MFMA, A regs, B from LDS)
#pragma unroll
        for (int mt = 0; mt < 4; ++mt)
#pragma unroll
            for (int nt = 0; nt < 4; ++nt) {
                bf16x4 vf = *(const bf16x4*)(&Vts[vaddr[mt] + nt * 1024]);
                of[0][nt] = __builtin_amdgcn_mfma_f32_16x16x16bf16_1k(aP[mt][0], vf, of[0][nt], 0, 0, 0);
                of[1][nt] = __builtin_amdgcn_mfma_f32_16x16x16bf16_1k(aP[mt][1], vf, of[1][nt], 0, 0, 0);
            }
    };

    for (int kt = 0; kt < NKT; kt += 2) {
        halfiter(kt,     kfA, kfB, vpA, vpB);
        halfiter(kt + 1, kfB, kfA, vpB, vpA);
    }

    // row-sum reduce over quads; then fetch per-O-row inverse
#pragma unroll
    for (int nt = 0; nt < 2; ++nt) {
        lp[nt] += __shfl_xor(lp[nt], 16, 64);
        lp[nt] += __shfl_xor(lp[nt], 32, 64);
    }
    float linv[2][4];
#pragma unroll
    for (int mtP = 0; mtP < 2; ++mtP)
#pragma unroll
        for (int r = 0; r < 4; ++r)
            linv[mtP][r] = 1.0f / __shfl(lp[mtP], quad * 4 + r, 64);

    const size_t base = ((size_t)b * SEQ + q0) * DMODEL + h * DK;
#pragma unroll
    for (int mtP = 0; mtP < 2; ++mtP)
#pragma unroll
        for (int nt = 0; nt < 4; ++nt)
#pragma unroll
            for (int r = 0; r < 4; ++r) {
                const float v = of[mtP][nt][r] * linv[mtP][r];
                const size_t idx = base + (size_t)(mtP * 16 + quad * 4 + r) * DMODEL + nt * 16 + ln;
                ctxh[idx] = __float2bfloat16(v);
            }
}

extern "C" void kernel_launch(void* const* d_in, const int* in_sizes, int n_in,
                              void* d_out, int out_size, void* d_ws, size_t ws_size,
                              hipStream_t stream) {
    const float* q  = (const float*)d_in[0];
    const float* k  = (const float*)d_in[1];
    const float* v  = (const float*)d_in[2];
    const float* wq = (const float*)d_in[3];
    const float* bq = (const float*)d_in[4];
    const float* wk = (const float*)d_in[5];
    const float* bk = (const float*)d_in[6];
    const float* wv = (const float*)d_in[7];
    const float* bv = (const float*)d_in[8];
    const float* wo = (const float*)d_in[9];
    const float* bo = (const float*)d_in[10];
    float* out = (float*)d_out;

    char* ws = (char*)d_ws;
    const size_t MB = 1u << 20;
    bf16* wq_hi = (bf16*)(ws + 0 * MB);    // 2 MB each
    bf16* wk_hi = (bf16*)(ws + 2 * MB);
    bf16* wv_hi = (bf16*)(ws + 4 * MB);
    bf16* wo_hi = (bf16*)(ws + 6 * MB);
    bf16* q_hi  = (bf16*)(ws + 8 * MB);    // 8 MB each; dead after qkv_gemm
    bf16* k_hi  = (bf16*)(ws + 16 * MB);
    bf16* v_hi  = (bf16*)(ws + 24 * MB);
    bf16* Qp    = (bf16*)(ws + 32 * MB);   // dead after flash
    bf16* Kp    = (bf16*)(ws + 40 * MB);
    bf16* Vpt   = (bf16*)(ws + 48 * MB);
    bf16* ctx_h = (bf16*)(ws + 8 * MB);    // overlays dead q_hi
    float* p0   = (float*)(ws + 16 * MB);  // 16 MB, overlays dead k_hi/v_hi
    float* p1   = (float*)(ws + 32 * MB);  // 16 MB, overlays dead Qp/Kp

    const int NX = M_TOT * DMODEL;   // 4M

    conv_all<<<dim3(NX / 1024, 4), 256, 0, stream>>>(
        q, k, v, wq, wk, wv, wo,
        q_hi, k_hi, v_hi, wq_hi, wk_hi, wv_hi, wo_hi);

    QKVArgs qa;
    qa.A[0] = q_hi;  qa.A[1] = k_hi;  qa.A[2] = v_hi;
    qa.W[0] = wq_hi; qa.W[1] = wk_hi; qa.W[2] = wv_hi;
    qa.bias[0] = bq; qa.bias[1] = bk; qa.bias[2] = bv;
    qa.out[0] = Qp;  qa.out[1] = Kp;  qa.out[2] = Vpt;
    qa.scale[0] = QSCALE; qa.scale[1] = 1.0f; qa.scale[2] = 1.0f;
    qa.layout[0] = 1; qa.layout[1] = 1; qa.layout[2] = 2;

    dim3 qgrid(DMODEL / 128, M_TOT / 128, 3);   // (8, 32, 3)
    qkv_gemm<<<qgrid, 256, 0, stream>>>(qa);

    dim3 fgrid(SEQ / 128, BATCH * NHEAD);       // (16, 32) = 512 blocks
    flash_attn_mfma<<<fgrid, 256, 0, stream>>>(Qp, Kp, Vpt, ctx_h);

    dim3 ogrid(DMODEL / 128, M_TOT / 128, 2);   // (8, 32, 2) split-K
    gemm_o<<<ogrid, 256, 0, stream>>>(ctx_h, wo_hi, p0, p1);

    combine_o<<<NX / 1024, 256, 0, stream>>>(p0, p1, bo, out);
}

// Round 8
// 260.259 us; speedup vs baseline: 1.3828x; 1.1674x over previous
//
#include <hip/hip_runtime.h>
#include <hip/hip_bf16.h>
#include <math.h>

// Problem constants (B=2, S=2048, D=1024, H=16, dk=64)
#define BATCH 2
#define SEQ   2048
#define DMODEL 1024
#define NHEAD 16
#define DK    64
#define M_TOT (BATCH*SEQ)      // 4096
#define KDIM  DMODEL           // 1024

typedef short bf16x8 __attribute__((ext_vector_type(8)));
typedef short bf16x4 __attribute__((ext_vector_type(4)));
typedef float f32x4  __attribute__((ext_vector_type(4)));
typedef __hip_bfloat16 bf16;

// 0.125 * log2(e) : folded into Q projection so softmax is exp2 directly
#define QSCALE 0.18033688011112042f

__device__ inline void gld_lds16(const void* g, void* l) {
    __builtin_amdgcn_global_load_lds(
        (const __attribute__((address_space(1))) unsigned int*)g,
        (__attribute__((address_space(3))) unsigned int*)l, 16, 0, 0);
}

__device__ inline unsigned pack2(float a, float b) {
    union { __hip_bfloat162 h; unsigned u; } t;
    t.h = __float22bfloat162_rn(make_float2(a, b));
    return t.u;
}

// ---- fused pre-pass. y=0..2: q/k/v fp32->bf16 (4M elems each).
// y=3: the four 1M-elem weights packed into a 4M range (all hi-only now).
__global__ __launch_bounds__(256) void conv_all(
    const float* __restrict__ q, const float* __restrict__ k, const float* __restrict__ v,
    const float* __restrict__ wq, const float* __restrict__ wk,
    const float* __restrict__ wv, const float* __restrict__ wo,
    bf16* __restrict__ qh, bf16* __restrict__ kh, bf16* __restrict__ vh,
    bf16* __restrict__ wqh, bf16* __restrict__ wkh, bf16* __restrict__ wvh,
    bf16* __restrict__ woh)
{
    const int y = blockIdx.y;
    const int i = (blockIdx.x * 256 + threadIdx.x) * 4;
    if (y < 3) {
        const float* src = y == 0 ? q : (y == 1 ? k : v);
        bf16* dst = y == 0 ? qh : (y == 1 ? kh : vh);
        float4 t = *(const float4*)(src + i);
        uint2 o;
        o.x = pack2(t.x, t.y);
        o.y = pack2(t.z, t.w);
        *(uint2*)(dst + i) = o;
    } else {
        const int w = i >> 20;               // 0..3 -> wq,wk,wv,wo
        const int j = i & ((1 << 20) - 1);
        const float* src = w == 0 ? wq : (w == 1 ? wk : (w == 2 ? wv : wo));
        bf16* dsth = w == 0 ? wqh : (w == 1 ? wkh : (w == 2 ? wvh : woh));
        float4 t = *(const float4*)(src + j);
        uint2 oh;
        oh.x = pack2(t.x, t.y);
        oh.y = pack2(t.z, t.w);
        *(uint2*)(dsth + j) = oh;
    }
}

// ---- MFMA GEMM body: C[M,N] = A @ W^T (+ bias), bf16 [rows, 1024].
// 128x128 tile, BK=32, 4 waves.
// layout 0: f32 [M,1024] +bias; 1: bf16 [B,H,S,dk] (*scale); 2: bf16 [B,H,dk,S];
// layout 3: f32 [M,1024] raw partial (no bias).  K range [kb, ke).
__device__ __forceinline__ void gemm_body(
    const bf16* __restrict__ Ah, const bf16* __restrict__ Wh,
    const float* __restrict__ bias, void* __restrict__ out,
    int layout, float scale, bf16* sA, bf16* sB, int kb, int ke)
{
    const int tid  = threadIdx.x;
    const int wave = tid >> 6, lane = tid & 63;
    const int ln   = lane & 15, quad = lane >> 4;
    const int wm   = wave >> 1, wn = wave & 1;
    const int row0 = blockIdx.y * 128, col0 = blockIdx.x * 128;

    const int srow = lane >> 2;
    const int clog = (lane & 3) ^ (srow & 3);
    const size_t gA0 = (size_t)(row0 + wave * 16 + srow) * KDIM + clog * 8;
    const size_t gB0 = (size_t)(col0 + wave * 16 + srow) * KDIM + clog * 8;
    const int ldsoff = (wave * 16 + srow) * 64 + (lane & 3) * 16;   // bytes

    const int swz = (quad ^ (ln & 3)) * 8;

    f32x4 acc[4][4] = {};

    for (int k0 = kb; k0 < ke; k0 += 32) {
        __syncthreads();
#pragma unroll
        for (int j = 0; j < 2; ++j) {
            const size_t go = (size_t)k0 + (size_t)j * 64 * KDIM;
            gld_lds16(Ah + gA0 + go, (char*)sA + j * 4096 + ldsoff);
            gld_lds16(Wh + gB0 + go, (char*)sB + j * 4096 + ldsoff);
        }
        __syncthreads();

        bf16x8 af[4], bfr[4];
#pragma unroll
        for (int t = 0; t < 4; ++t) {
            af[t]  = *(const bf16x8*)&sA[(wm * 64 + t * 16 + ln) * 32 + swz];
            bfr[t] = *(const bf16x8*)&sB[(wn * 64 + t * 16 + ln) * 32 + swz];
        }
#pragma unroll
        for (int mt = 0; mt < 4; ++mt)
#pragma unroll
            for (int nt = 0; nt < 4; ++nt)
                acc[mt][nt] = __builtin_amdgcn_mfma_f32_16x16x32_bf16(af[mt], bfr[nt], acc[mt][nt], 0, 0, 0);
    }

#pragma unroll
    for (int nt = 0; nt < 4; ++nt) {
        const int n = col0 + wn * 64 + nt * 16 + ln;
        const float bv = (layout == 3) ? 0.f : bias[n];
#pragma unroll
        for (int mt = 0; mt < 4; ++mt) {
#pragma unroll
            for (int r = 0; r < 4; ++r) {
                const int m = row0 + wm * 64 + mt * 16 + quad * 4 + r;
                const float v = (acc[mt][nt][r] + bv) * scale;
                if (layout == 0 || layout == 3) {
                    ((float*)out)[(size_t)m * DMODEL + n] = v;
                } else {
                    const int b = m >> 11, s = m & (SEQ - 1);
                    const int h = n >> 6,  d = n & (DK - 1);
                    const int bh = b * NHEAD + h;
                    bf16 hv = __float2bfloat16(v);
                    if (layout == 1)
                        ((bf16*)out)[((size_t)bh * SEQ + s) * DK + d] = hv;
                    else
                        ((bf16*)out)[((size_t)bh * DK + d) * SEQ + s] = hv;
                }
            }
        }
    }
}

struct QKVArgs {
    const bf16* A[3];
    const bf16* W[3];
    const float* bias[3];
    bf16* out[3];
    float scale[3];
    int layout[3];
};

__global__ __launch_bounds__(256) void qkv_gemm(QKVArgs a) {
    __shared__ __align__(16) bf16 sA[128 * 32];
    __shared__ __align__(16) bf16 sB[128 * 32];
    const int z = blockIdx.z;
    gemm_body(a.A[z], a.W[z], a.bias[z],
              (void*)a.out[z], a.layout[z], a.scale[z], sA, sB, 0, KDIM);
}

// O projection, plain bf16, split-K x2: z selects K half, f32 partial.
__global__ __launch_bounds__(256) void gemm_o(
    const bf16* __restrict__ Ah, const bf16* __restrict__ Wh,
    float* __restrict__ p0, float* __restrict__ p1)
{
    __shared__ __align__(16) bf16 sA[128 * 32];
    __shared__ __align__(16) bf16 sB[128 * 32];
    const int z = blockIdx.z;
    gemm_body(Ah, Wh, nullptr, (void*)(z ? p1 : p0), 3, 1.0f,
              sA, sB, z * (KDIM / 2), (z + 1) * (KDIM / 2));
}

__global__ __launch_bounds__(256) void combine_o(
    const float* __restrict__ p0, const float* __restrict__ p1,
    const float* __restrict__ bias, float* __restrict__ out)
{
    const int i = (blockIdx.x * 256 + threadIdx.x) * 4;
    float4 a = *(const float4*)(p0 + i);
    float4 b = *(const float4*)(p1 + i);
    float4 c = *(const float4*)(bias + (i & (DMODEL - 1)));
    float4 o;
    o.x = a.x + b.x + c.x;
    o.y = a.y + b.y + c.y;
    o.z = a.z + b.z + c.z;
    o.w = a.w + b.w + c.w;
    *(float4*)(out + i) = o;
}

// ---- MFMA flash attention: round-0 structure VERBATIM (proven 78us:
// 256 thr, 4 waves, 32 q/wave, standard __syncthreads, K double-register
// prefetch, V loaded between the barriers) + ONLY the XCD swizzle added
// (r7 A/B: swizzle's FETCH 70->13MB effect is proven; r7's inner-loop
// restructure is the regression suspect and is fully reverted here).
#define NKT (SEQ / 64)
__global__ __launch_bounds__(256) void flash_attn_mfma(
    const bf16* __restrict__ Q, const bf16* __restrict__ K,
    const bf16* __restrict__ Vt, bf16* __restrict__ ctxh)
{
    __shared__ __align__(16) bf16 Vts[64 * 64];

    const int tid  = threadIdx.x;
    const int wave = tid >> 6, lane = tid & 63;
    const int ln   = lane & 15, quad = lane >> 4;

    // XCD-aware swizzle (bijective on 512 blocks = 8 xcd * 4 heads * 16 qt):
    // all 16 q-tiles of one head share one XCD (per-head KV 512KB << 4MB L2).
    const int lin  = blockIdx.y * gridDim.x + blockIdx.x;   // 0..511
    const int slot = lin >> 3;                              // 0..63
    const int bh   = (lin & 7) * 4 + (slot >> 4);           // 4 heads per XCD
    const int qt   = slot & 15;                             // 128-row q tile
    const int b    = bh >> 4, h = bh & (NHEAD - 1);

    const int q0 = qt * 128 + wave * 32;
    const bf16* Qb = Q + ((size_t)bh * SEQ + q0) * DK;
    bf16x8 qf[2][2];
#pragma unroll
    for (int c = 0; c < 2; ++c)
#pragma unroll
        for (int nt = 0; nt < 2; ++nt)
            qf[c][nt] = *(const bf16x8*)(Qb + (size_t)(nt * 16 + ln) * DK + c * 32 + quad * 8);

    f32x4 of[2][4] = {};
    float lp[2] = {0.f, 0.f};

    const int sr  = tid >> 2;          // 0..63 (dk row of Vt)
    const int scb = (tid & 3) * 2;
    const int ssw = sr & 7;
    const bf16* Vg0 = Vt + ((size_t)bh * DK + sr) * SEQ;
    const bf16* Kl  = K + (size_t)bh * SEQ * DK + (size_t)ln * DK + quad * 8;

    // PV B-frag LDS addresses (kt-invariant, elements)
    int vaddr[4];
#pragma unroll
    for (int mt = 0; mt < 4; ++mt)
        vaddr[mt] = ln * 64 + (((2 * mt + (quad >> 1)) ^ (ln & 7)) * 8) + (quad & 1) * 4;

    bf16x8 kfA[2][4], kfB[2][4];
#pragma unroll
    for (int c = 0; c < 2; ++c)
#pragma unroll
        for (int mt = 0; mt < 4; ++mt)
            kfA[c][mt] = *(const bf16x8*)(Kl + (size_t)(mt * 16) * DK + c * 32);

    auto halfiter = [&](int ktc, bf16x8 (&kfc)[2][4], bf16x8 (&kfn)[2][4]) {
        __syncthreads();
        {
            const bf16* Vg = Vg0 + ktc * 64;
            uint4 v0 = *(const uint4*)(Vg + scb * 8);
            uint4 v1 = *(const uint4*)(Vg + scb * 8 + 8);
            *(uint4*)(&Vts[sr * 64 + ((scb    ) ^ ssw) * 8]) = v0;
            *(uint4*)(&Vts[sr * 64 + ((scb + 1) ^ ssw) * 8]) = v1;
        }
        __syncthreads();

        // prefetch next tile's K frags into the alternate register set
        const int ktn = (ktc + 1) & (NKT - 1);
#pragma unroll
        for (int c = 0; c < 2; ++c)
#pragma unroll
            for (int mt = 0; mt < 4; ++mt)
                kfn[c][mt] = *(const bf16x8*)(Kl + (size_t)(ktn * 64 + mt * 16) * DK + c * 32);

        // S^T[kv=64][q=32] = K @ Q^T  (x32 MFMA)
        f32x4 st[4][2] = {};
#pragma unroll
        for (int c = 0; c < 2; ++c)
#pragma unroll
            for (int mt = 0; mt < 4; ++mt)
#pragma unroll
                for (int nt = 0; nt < 2; ++nt)
                    st[mt][nt] = __builtin_amdgcn_mfma_f32_16x16x32_bf16(kfc[c][mt], qf[c][nt], st[mt][nt], 0, 0, 0);

        // P = exp2(S) -> x16 A-frags in registers; lp partials
        bf16x4 aP[4][2];
#pragma unroll
        for (int mt = 0; mt < 4; ++mt)
#pragma unroll
            for (int nt = 0; nt < 2; ++nt) {
                float p0 = __builtin_amdgcn_exp2f(st[mt][nt][0]);
                float p1 = __builtin_amdgcn_exp2f(st[mt][nt][1]);
                float p2 = __builtin_amdgcn_exp2f(st[mt][nt][2]);
                float p3 = __builtin_amdgcn_exp2f(st[mt][nt][3]);
                lp[nt] += (p0 + p1) + (p2 + p3);
                union { bf16x4 v; uint2 u; } uu;
                uu.u.x = pack2(p0, p1);
                uu.u.y = pack2(p2, p3);
                aP[mt][nt] = uu.v;
            }

        // O[q=32][dk=64] += P @ V  (x16 MFMA, A regs, B from LDS)
#pragma unroll
        for (int mt = 0; mt < 4; ++mt)
#pragma unroll
            for (int nt = 0; nt < 4; ++nt) {
                bf16x4 vf = *(const bf16x4*)(&Vts[vaddr[mt] + nt * 1024]);
                of[0][nt] = __builtin_amdgcn_mfma_f32_16x16x16bf16_1k(aP[mt][0], vf, of[0][nt], 0, 0, 0);
                of[1][nt] = __builtin_amdgcn_mfma_f32_16x16x16bf16_1k(aP[mt][1], vf, of[1][nt], 0, 0, 0);
            }
    };

    for (int kt = 0; kt < NKT; kt += 2) {
        halfiter(kt,     kfA, kfB);
        halfiter(kt + 1, kfB, kfA);
    }

    // row-sum reduce over quads; then fetch per-O-row inverse
#pragma unroll
    for (int nt = 0; nt < 2; ++nt) {
        lp[nt] += __shfl_xor(lp[nt], 16, 64);
        lp[nt] += __shfl_xor(lp[nt], 32, 64);
    }
    float linv[2][4];
#pragma unroll
    for (int mtP = 0; mtP < 2; ++mtP)
#pragma unroll
        for (int r = 0; r < 4; ++r)
            linv[mtP][r] = 1.0f / __shfl(lp[mtP], quad * 4 + r, 64);

    const size_t base = ((size_t)b * SEQ + q0) * DMODEL + h * DK;
#pragma unroll
    for (int mtP = 0; mtP < 2; ++mtP)
#pragma unroll
        for (int nt = 0; nt < 4; ++nt)
#pragma unroll
            for (int r = 0; r < 4; ++r) {
                const float v = of[mtP][nt][r] * linv[mtP][r];
                const size_t idx = base + (size_t)(mtP * 16 + quad * 4 + r) * DMODEL + nt * 16 + ln;
                ctxh[idx] = __float2bfloat16(v);
            }
}

extern "C" void kernel_launch(void* const* d_in, const int* in_sizes, int n_in,
                              void* d_out, int out_size, void* d_ws, size_t ws_size,
                              hipStream_t stream) {
    const float* q  = (const float*)d_in[0];
    const float* k  = (const float*)d_in[1];
    const float* v  = (const float*)d_in[2];
    const float* wq = (const float*)d_in[3];
    const float* bq = (const float*)d_in[4];
    const float* wk = (const float*)d_in[5];
    const float* bk = (const float*)d_in[6];
    const float* wv = (const float*)d_in[7];
    const float* bv = (const float*)d_in[8];
    const float* wo = (const float*)d_in[9];
    const float* bo = (const float*)d_in[10];
    float* out = (float*)d_out;

    char* ws = (char*)d_ws;
    const size_t MB = 1u << 20;
    bf16* wq_hi = (bf16*)(ws + 0 * MB);    // 2 MB each
    bf16* wk_hi = (bf16*)(ws + 2 * MB);
    bf16* wv_hi = (bf16*)(ws + 4 * MB);
    bf16* wo_hi = (bf16*)(ws + 6 * MB);
    bf16* q_hi  = (bf16*)(ws + 8 * MB);    // 8 MB each; dead after qkv_gemm
    bf16* k_hi  = (bf16*)(ws + 16 * MB);
    bf16* v_hi  = (bf16*)(ws + 24 * MB);
    bf16* Qp    = (bf16*)(ws + 32 * MB);   // dead after flash
    bf16* Kp    = (bf16*)(ws + 40 * MB);
    bf16* Vpt   = (bf16*)(ws + 48 * MB);
    bf16* ctx_h = (bf16*)(ws + 8 * MB);    // overlays dead q_hi
    float* p0   = (float*)(ws + 16 * MB);  // 16 MB, overlays dead k_hi/v_hi
    float* p1   = (float*)(ws + 32 * MB);  // 16 MB, overlays dead Qp/Kp

    const int NX = M_TOT * DMODEL;   // 4M

    conv_all<<<dim3(NX / 1024, 4), 256, 0, stream>>>(
        q, k, v, wq, wk, wv, wo,
        q_hi, k_hi, v_hi, wq_hi, wk_hi, wv_hi, wo_hi);

    QKVArgs qa;
    qa.A[0] = q_hi;  qa.A[1] = k_hi;  qa.A[2] = v_hi;
    qa.W[0] = wq_hi; qa.W[1] = wk_hi; qa.W[2] = wv_hi;
    qa.bias[0] = bq; qa.bias[1] = bk; qa.bias[2] = bv;
    qa.out[0] = Qp;  qa.out[1] = Kp;  qa.out[2] = Vpt;
    qa.scale[0] = QSCALE; qa.scale[1] = 1.0f; qa.scale[2] = 1.0f;
    qa.layout[0] = 1; qa.layout[1] = 1; qa.layout[2] = 2;

    dim3 qgrid(DMODEL / 128, M_TOT / 128, 3);   // (8, 32, 3)
    qkv_gemm<<<qgrid, 256, 0, stream>>>(qa);

    dim3 fgrid(SEQ / 128, BATCH * NHEAD);       // (16, 32) = 512 blocks
    flash_attn_mfma<<<fgrid, 256, 0, stream>>>(Qp, Kp, Vpt, ctx_h);

    dim3 ogrid(DMODEL / 128, M_TOT / 128, 2);   // (8, 32, 2) split-K
    gemm_o<<<ogrid, 256, 0, stream>>>(ctx_h, wo_hi, p0, p1);

    combine_o<<<NX / 1024, 256, 0, stream>>>(p0, p1, bo, out);
}